// Round 2
// baseline (1961.860 us; speedup 1.0000x reference)
//
#include <hip/hip_runtime.h>
#include <math.h>

#define PH_N   2048
#define PH_B   16
#define PH_F   50
#define TPB    512
#define PTS    (PH_N / TPB)      // 4 points per thread
#define NWAVES (TPB / 64)        // 8 waves
#define MAXPTS 100

// Distance exactly as the reference computes it:
// d2 = (sq_p + sq_q) - 2*dot(p,q);  d = sqrt(max(d2, 0))
// Explicit _rn intrinsics so the compiler cannot fma-contract and drift from
// the reference arithmetic (Betti counts are integer-sensitive to deaths
// crossing filtration thresholds).
__device__ __forceinline__ float distf(float4 p, float4 q) {
    float dot = __fadd_rn(__fadd_rn(__fmul_rn(p.x, q.x), __fmul_rn(p.y, q.y)),
                          __fmul_rn(p.z, q.z));
    float d2 = __fsub_rn(__fadd_rn(p.w, q.w), __fmul_rn(2.0f, dot));
    return sqrtf(fmaxf(d2, 0.0f));
}

__global__ __launch_bounds__(TPB)
void ph_mst_kernel(const float* __restrict__ x,
                   const float* __restrict__ filt,
                   float* __restrict__ out) {
    __shared__ float4 pts[PH_N];       // {x, y, z, |p|^2}
    __shared__ float  deaths[PH_N];    // [0..N-2] deaths, [N-1] = -inf pad
    __shared__ float  wv[2][NWAVES];   // double-buffered per-wave argmin partials
    __shared__ int    wi[2][NWAVES];
    __shared__ int    cnt[PH_F];

    const int b   = blockIdx.x;
    const int tid = threadIdx.x;
    const float* xb = x + (size_t)b * PH_N * 3;
    const float INF = __builtin_inff();

    // ---- stage points + squared norms into LDS as float4 ----
    for (int i = tid; i < PH_N; i += TPB) {
        float px = xb[i * 3 + 0];
        float py = xb[i * 3 + 1];
        float pz = xb[i * 3 + 2];
        float s  = __fadd_rn(__fadd_rn(__fmul_rn(px, px), __fmul_rn(py, py)),
                             __fmul_rn(pz, pz));
        pts[i] = make_float4(px, py, pz, s);
    }
    __syncthreads();

    // Each thread owns points tid + k*TPB, k = 0..PTS-1 (registers).
    float4 P[PTS];
    float  md[PTS];
    bool   fl[PTS];
    #pragma unroll
    for (int k = 0; k < PTS; ++k) {
        P[k]  = pts[tid + k * TPB];
        fl[k] = false;
    }
    // init: vertex 0 in tree, min_dist = D[0][:]
    const float4 a0 = pts[0];
    #pragma unroll
    for (int k = 0; k < PTS; ++k) md[k] = distf(P[k], a0);
    fl[0] = (tid == 0);

    // ---- Prim's algorithm: N-1 iterations, ONE barrier per iteration ----
    int par = 0;
    for (int it = 0; it < PH_N - 1; ++it) {
        // per-thread masked argmin over owned points
        float v  = INF;
        int  idx = 0;
        #pragma unroll
        for (int k = 0; k < PTS; ++k) {
            float vv = fl[k] ? INF : md[k];
            if (vv < v) { v = vv; idx = tid + k * TPB; }
        }
        // wave-level argmin (64 lanes)
        #pragma unroll
        for (int off = 32; off > 0; off >>= 1) {
            float ov = __shfl_xor(v, off);
            int   oi = __shfl_xor(idx, off);
            if (ov < v) { v = ov; idx = oi; }
        }
        if ((tid & 63) == 0) {
            wv[par][tid >> 6] = v;
            wi[par][tid >> 6] = idx;
        }
        __syncthreads();

        // every thread scans the 8 wave partials (LDS broadcast reads).
        // Double buffering makes next iteration's writes go to wv[par^1],
        // so no trailing barrier is needed to guard this read.
        float bw = wv[par][0];
        int   j  = wi[par][0];
        #pragma unroll
        for (int kk = 1; kk < NWAVES; ++kk) {
            float vv = wv[par][kk];
            if (vv < bw) { bw = vv; j = wi[par][kk]; }
        }
        if (tid == 0) deaths[it] = bw;

        // update min_dist with distances to the newly added vertex j
        const float4 q = pts[j];   // single ds_read_b128 broadcast
        #pragma unroll
        for (int k = 0; k < PTS; ++k) {
            if (j == tid + k * TPB) fl[k] = true;
            md[k] = fminf(md[k], distf(P[k], q));
        }
        par ^= 1;
    }

    if (tid == 0) deaths[PH_N - 1] = -INF;   // pad to power of two
    __syncthreads();

    // ---- bitonic sort ascending over deaths[0..N-1] in LDS ----
    for (int k = 2; k <= PH_N; k <<= 1) {
        for (int jj = k >> 1; jj > 0; jj >>= 1) {
            for (int i = tid; i < PH_N; i += TPB) {
                int ixj = i ^ jj;
                if (ixj > i) {
                    float a = deaths[i];
                    float c = deaths[ixj];
                    bool up = ((i & k) == 0);
                    if (up ? (a > c) : (a < c)) {
                        deaths[i]   = c;
                        deaths[ixj] = a;
                    }
                }
            }
            __syncthreads();
        }
    }

    // ---- Betti-0 counts: per-threshold binary search (upper bound) ----
    if (tid < PH_F) {
        float eps = filt[tid];
        int lo = 0, hi = PH_N;
        while (lo < hi) {
            int mid = (lo + hi) >> 1;
            if (deaths[mid] <= eps) lo = mid + 1; else hi = mid;
        }
        cnt[tid] = lo - 1;   // exclude the -inf pad
    }
    __syncthreads();

    // ---- write outputs ----
    // diagrams: [B,3,100,2] at out[0..9599]; plane 0 = (0, death_k), planes 1,2 = 0
    float* dg = out + (size_t)b * (3 * MAXPTS * 2);
    for (int t = tid; t < 3 * MAXPTS * 2; t += TPB) {
        float val = 0.0f;
        if (t < 2 * MAXPTS && (t & 1)) {
            int k = t >> 1;                      // k-th largest death
            val = deaths[PH_N - 1 - k];
        }
        dg[t] = val;
    }
    // betti curves: [B,3,50] at out[9600..11999]; plane 0 = N - count, planes 1,2 = 0
    float* bc = out + (size_t)PH_B * (3 * MAXPTS * 2) + (size_t)b * (3 * PH_F);
    for (int t = tid; t < 3 * PH_F; t += TPB) {
        float val = 0.0f;
        if (t < PH_F) val = (float)(PH_N - cnt[t]);
        bc[t] = val;
    }
}

extern "C" void kernel_launch(void* const* d_in, const int* in_sizes, int n_in,
                              void* d_out, int out_size, void* d_ws, size_t ws_size,
                              hipStream_t stream) {
    const float* x    = (const float*)d_in[0];
    const float* filt = (const float*)d_in[1];
    float* out        = (float*)d_out;

    ph_mst_kernel<<<dim3(PH_B), dim3(TPB), 0, stream>>>(x, filt, out);
}

// Round 4
// 1787.920 us; speedup vs baseline: 1.0973x; 1.0973x over previous
//
#include <hip/hip_runtime.h>
#include <math.h>

#define PH_N   2048
#define PH_B   16
#define PH_F   50
#define TPB    256
#define PTS    (PH_N / TPB)      // 8 points per thread
#define NWAVES (TPB / 64)        // 4 waves
#define MAXPTS 100

// Distance exactly as the reference computes it:
// d2 = (sq_p + sq_q) - 2*dot(p,q);  d = sqrt(max(d2, 0))
// Explicit _rn intrinsics so the compiler cannot fma-contract and drift from
// the reference arithmetic (Betti counts are integer-sensitive to deaths
// crossing filtration thresholds).
__device__ __forceinline__ float distf(float4 p, float4 q) {
    float dot = __fadd_rn(__fadd_rn(__fmul_rn(p.x, q.x), __fmul_rn(p.y, q.y)),
                          __fmul_rn(p.z, q.z));
    float d2 = __fsub_rn(__fadd_rn(p.w, q.w), __fmul_rn(2.0f, dot));
    return sqrtf(fmaxf(d2, 0.0f));
}

// One DPP min step at VALU speed (no LDS pipe). bound_ctrl=false + old=v:
// lanes with invalid DPP source keep their own value (min(v,v) harmless).
template<int CTRL>
__device__ __forceinline__ float dpp_min(float v) {
    int vi = __float_as_int(v);
    int sh = __builtin_amdgcn_update_dpp(vi, vi, CTRL, 0xF, 0xF, false);
    return fminf(v, __int_as_float(sh));
}

__global__ __launch_bounds__(TPB)
void ph_mst_kernel(const float* __restrict__ x,
                   const float* __restrict__ filt,
                   float* __restrict__ out) {
    __shared__ float4 pts[PH_N];       // {x, y, z, |p|^2}
    __shared__ float  deaths[PH_N];    // [0..N-2] deaths, [N-1] = -inf pad
    __shared__ float  wv[2][NWAVES];   // double-buffered per-wave argmin partials
    __shared__ int    wi[2][NWAVES];
    __shared__ int    cnt[PH_F];

    const int b   = blockIdx.x;
    const int tid = threadIdx.x;
    const float* xb = x + (size_t)b * PH_N * 3;
    const float INF = __builtin_inff();

    // ---- stage points + squared norms into LDS as float4 ----
    for (int i = tid; i < PH_N; i += TPB) {
        float px = xb[i * 3 + 0];
        float py = xb[i * 3 + 1];
        float pz = xb[i * 3 + 2];
        float s  = __fadd_rn(__fadd_rn(__fmul_rn(px, px), __fmul_rn(py, py)),
                             __fmul_rn(pz, pz));
        pts[i] = make_float4(px, py, pz, s);
    }
    __syncthreads();

    // Each thread owns points tid + k*TPB, k = 0..PTS-1 (registers).
    float4 P[PTS];
    float  md[PTS];
    bool   fl[PTS];
    #pragma unroll
    for (int k = 0; k < PTS; ++k) {
        P[k]  = pts[tid + k * TPB];
        fl[k] = false;
    }
    // init: vertex 0 in tree, min_dist = D[0][:]
    const float4 a0 = pts[0];
    #pragma unroll
    for (int k = 0; k < PTS; ++k) md[k] = distf(P[k], a0);
    fl[0] = (tid == 0);

    // ---- Prim's algorithm: N-1 iterations, ONE barrier per iteration ----
    int par = 0;
    for (int it = 0; it < PH_N - 1; ++it) {
        // per-thread masked argmin over owned points
        float v  = INF;
        int   kb = 0;
        #pragma unroll
        for (int k = 0; k < PTS; ++k) {
            float vv = fl[k] ? INF : md[k];
            if (vv < v) { v = vv; kb = k; }
        }
        const int myidx = tid + kb * TPB;

        // wave-level min via DPP (VALU-speed, ~60cy for the 6-step chain):
        // row_shr:1,2,4,8 then row_bcast15, row_bcast31 -> min in lane 63.
        float wmin = v;
        wmin = dpp_min<0x111>(wmin);   // row_shr:1
        wmin = dpp_min<0x112>(wmin);   // row_shr:2
        wmin = dpp_min<0x114>(wmin);   // row_shr:4
        wmin = dpp_min<0x118>(wmin);   // row_shr:8
        wmin = dpp_min<0x142>(wmin);   // row_bcast15
        wmin = dpp_min<0x143>(wmin);   // row_bcast31
        const float wm =
            __int_as_float(__builtin_amdgcn_readlane(__float_as_int(wmin), 63));

        // owner lane via ballot (wm is bit-exact equal to some lane's v)
        unsigned long long msk = __ballot(v == wm);
        const int lane  = (int)__ffsll(msk) - 1;
        const int widx_ = __builtin_amdgcn_readlane(myidx, lane);

        if ((tid & 63) == 0) {
            wv[par][tid >> 6] = wm;
            wi[par][tid >> 6] = widx_;
        }
        __syncthreads();

        // cross-wave scan of the NWAVES partials (one b128-able row each).
        // Double buffering: next iteration writes wv[par^1], so no trailing
        // barrier is needed to guard these reads.
        float bw = wv[par][0];
        int   j  = wi[par][0];
        #pragma unroll
        for (int q = 1; q < NWAVES; ++q) {
            float vv = wv[par][q];
            if (vv < bw) { bw = vv; j = wi[par][q]; }
        }
        if (tid == 0) deaths[it] = bw;

        // update min_dist with distances to the newly added vertex j
        const float4 qq = pts[j];   // single ds_read_b128 broadcast
        #pragma unroll
        for (int k = 0; k < PTS; ++k) {
            if (j == tid + k * TPB) fl[k] = true;
            md[k] = fminf(md[k], distf(P[k], qq));
        }
        par ^= 1;
    }

    if (tid == 0) deaths[PH_N - 1] = -INF;   // pad to power of two
    __syncthreads();

    // ---- bitonic sort ascending over deaths[0..N-1] in LDS ----
    for (int k = 2; k <= PH_N; k <<= 1) {
        for (int jj = k >> 1; jj > 0; jj >>= 1) {
            for (int i = tid; i < PH_N; i += TPB) {
                int ixj = i ^ jj;
                if (ixj > i) {
                    float a = deaths[i];
                    float c = deaths[ixj];
                    bool up = ((i & k) == 0);
                    if (up ? (a > c) : (a < c)) {
                        deaths[i]   = c;
                        deaths[ixj] = a;
                    }
                }
            }
            __syncthreads();
        }
    }

    // ---- Betti-0 counts: per-threshold binary search (upper bound) ----
    if (tid < PH_F) {
        float eps = filt[tid];
        int lo = 0, hi = PH_N;
        while (lo < hi) {
            int mid = (lo + hi) >> 1;
            if (deaths[mid] <= eps) lo = mid + 1; else hi = mid;
        }
        cnt[tid] = lo - 1;   // exclude the -inf pad
    }
    __syncthreads();

    // ---- write outputs ----
    // diagrams: [B,3,100,2] at out[0..9599]; plane 0 = (0, death_k), planes 1,2 = 0
    float* dg = out + (size_t)b * (3 * MAXPTS * 2);
    for (int t = tid; t < 3 * MAXPTS * 2; t += TPB) {
        float val = 0.0f;
        if (t < 2 * MAXPTS && (t & 1)) {
            int k = t >> 1;                      // k-th largest death
            val = deaths[PH_N - 1 - k];
        }
        dg[t] = val;
    }
    // betti curves: [B,3,50] at out[9600..11999]; plane 0 = N - count, planes 1,2 = 0
    float* bc = out + (size_t)PH_B * (3 * MAXPTS * 2) + (size_t)b * (3 * PH_F);
    for (int t = tid; t < 3 * PH_F; t += TPB) {
        float val = 0.0f;
        if (t < PH_F) val = (float)(PH_N - cnt[t]);
        bc[t] = val;
    }
}

extern "C" void kernel_launch(void* const* d_in, const int* in_sizes, int n_in,
                              void* d_out, int out_size, void* d_ws, size_t ws_size,
                              hipStream_t stream) {
    const float* x    = (const float*)d_in[0];
    const float* filt = (const float*)d_in[1];
    float* out        = (float*)d_out;

    ph_mst_kernel<<<dim3(PH_B), dim3(TPB), 0, stream>>>(x, filt, out);
}

// Round 7
// 446.719 us; speedup vs baseline: 4.3917x; 4.0023x over previous
//
#include <hip/hip_runtime.h>
#include <math.h>

// Boruvka MST persistent-homology kernel.
// Correctness: all MSTs under a strict total edge order share the MST; the
// death outputs depend only on the MST weight multiset, which is identical
// for ALL MSTs under any tie-break refinement. We order edges by the key
// (d2_bits, min(i,j), max(i,j)) — a strict refinement of the reference's
// sqrt-domain weight order (sqrtf is correctly rounded => monotone). d2 is
// computed in the reference's exact f32 op order and clamped, sqrtf applied
// once at the end => bit-exact outputs vs the reference's Prim.
// Per-row tie-break: for fixed row i, minimizing the full key on equal d2
// equals picking the smallest j (case split on min/max(i,j)) — implemented
// as lowest-k in-lane + cross-lane DPP int-min over j among d2-tied lanes.

#define PH_N   2048
#define PH_B   16
#define PH_F   50
#define MAXPTS 100
#define ROUNDS 11            // ceil(log2(N)) guaranteed convergence
#define RB     16            // row-blocks per batch in k_best
#define RPB    (PH_N / RB)   // 128 rows per block
#define KA_TPB 256
#define JPL    32            // j's per lane (2048/64)

typedef unsigned long long u64;
typedef unsigned int u32;

__device__ __forceinline__ float sq3(float x, float y, float z) {
    return __fadd_rn(__fadd_rn(__fmul_rn(x, x), __fmul_rn(y, y)), __fmul_rn(z, z));
}
// d2 exactly as reference: (sq_p + sq_q) - 2*dot, no fma contraction
__device__ __forceinline__ float d2f(float px, float py, float pz, float ps,
                                     float qx, float qy, float qz, float qs) {
    float dot = __fadd_rn(__fadd_rn(__fmul_rn(px, qx), __fmul_rn(py, qy)),
                          __fmul_rn(pz, qz));
    return __fsub_rn(__fadd_rn(ps, qs), __fmul_rn(2.0f, dot));
}

template<int CTRL>
__device__ __forceinline__ float dpp_min(float v) {
    int vi = __float_as_int(v);
    int sh = __builtin_amdgcn_update_dpp(vi, vi, CTRL, 0xF, 0xF, false);
    return fminf(v, __int_as_float(sh));
}
template<int CTRL>
__device__ __forceinline__ int dpp_imin(int v) {
    int sh = __builtin_amdgcn_update_dpp(v, v, CTRL, 0xF, 0xF, false);
    return min(v, sh);
}

__global__ void k_init(int* __restrict__ comp, u64* __restrict__ compBest,
                       int* __restrict__ cnt) {
    const int b = blockIdx.x, tid = threadIdx.x;
    for (int i = tid; i < PH_N; i += blockDim.x) {
        comp[b * PH_N + i]     = i;
        compBest[b * PH_N + i] = ~0ULL;
    }
    if (tid == 0) cnt[b] = 0;
}

// Per round: each vertex (row i) finds its min-key edge to another component;
// per-component min via LDS u64 atomicMin, then merged to global.
__global__ __launch_bounds__(KA_TPB, 1)
void k_best(const float* __restrict__ x, const int* __restrict__ comp,
            u64* __restrict__ compBest) {
    __shared__ float4 spts[PH_N];    // 32 KB {x,y,z,|p|^2}
    __shared__ int    scomp[PH_N];   // 8 KB
    __shared__ u64    sbest[PH_N];   // 16 KB
    __shared__ int    sconv;

    const int b = blockIdx.y, rb = blockIdx.x, tid = threadIdx.x;
    const int lane = tid & 63, wave = tid >> 6;
    const float* xb = x + (size_t)b * PH_N * 3;
    if (tid == 0) sconv = 1;

    for (int i = tid; i < PH_N; i += KA_TPB) {
        float px = xb[3 * i], py = xb[3 * i + 1], pz = xb[3 * i + 2];
        spts[i]  = make_float4(px, py, pz, sq3(px, py, pz));
        scomp[i] = comp[b * PH_N + i];
        sbest[i] = ~0ULL;
    }
    __syncthreads();

    // converged? (single component -> nothing to do this round)
    {
        int c0 = scomp[0];
        bool same = true;
        for (int i = tid; i < PH_N; i += KA_TPB) same &= (scomp[i] == c0);
        if (!same) sconv = 0;   // concurrent 0-writes benign; ordered by barrier
    }
    __syncthreads();
    if (sconv) return;

    // per-lane j-side caches in registers (lane owns j = lane + 64k)
    float xj[JPL], yj[JPL], zj[JPL], sj[JPL];
    int   cj[JPL];
    #pragma unroll
    for (int k = 0; k < JPL; ++k) {
        float4 qv = spts[lane + (k << 6)];
        xj[k] = qv.x; yj[k] = qv.y; zj[k] = qv.z; sj[k] = qv.w;
        cj[k] = scomp[lane + (k << 6)];
    }

    const float INF = __builtin_inff();
    for (int r = wave; r < RPB; r += KA_TPB / 64) {
        const int    i  = rb * RPB + r;
        const int    ci = scomp[i];
        const float4 pi = spts[i];
        float m[JPL]; int ix[JPL];
        #pragma unroll
        for (int k = 0; k < JPL; ++k) {
            float d2 = d2f(pi.x, pi.y, pi.z, pi.w, xj[k], yj[k], zj[k], sj[k]);
            d2   = fmaxf(d2, 0.0f);                 // = reference max(d2,0)
            m[k] = (cj[k] == ci) ? INF : d2;        // mask same-component (covers j==i)
            ix[k] = k;
        }
        // in-register argmin tree; on ties keeps lower k (= lower j per lane)
        #pragma unroll
        for (int s = JPL / 2; s > 0; s >>= 1) {
            #pragma unroll
            for (int k = 0; k < s; ++k)
                if (m[k + s] < m[k]) { m[k] = m[k + s]; ix[k] = ix[k + s]; }
        }
        const float vl = m[0];
        float w = vl;
        w = dpp_min<0x111>(w); w = dpp_min<0x112>(w); w = dpp_min<0x114>(w);
        w = dpp_min<0x118>(w); w = dpp_min<0x142>(w); w = dpp_min<0x143>(w);
        const float wm =
            __int_as_float(__builtin_amdgcn_readlane(__float_as_int(w), 63));
        if (wm < INF) {
            // full-key-consistent tie-break: among d2-tied lanes take min j
            int jw = lane + (ix[0] << 6);
            int jc = (vl == wm) ? jw : 0x7FFFFFFF;
            jc = dpp_imin<0x111>(jc); jc = dpp_imin<0x112>(jc);
            jc = dpp_imin<0x114>(jc); jc = dpp_imin<0x118>(jc);
            jc = dpp_imin<0x142>(jc); jc = dpp_imin<0x143>(jc);
            const int j = __builtin_amdgcn_readlane(jc, 63);
            if (lane == 0) {
                int a = min(i, j), c2 = max(i, j);
                u64 key = ((u64)__float_as_uint(wm) << 22) | ((u64)a << 11) | (u64)c2;
                atomicMin(&sbest[ci], key);
            }
        }
    }
    __syncthreads();
    for (int c = tid; c < PH_N; c += KA_TPB) {
        u64 k = sbest[c];
        if (k != ~0ULL) atomicMin(&compBest[(size_t)b * PH_N + c], k);
    }
}

// Merge (all in LDS): parent links, mutual-pair dedup (each MST edge recorded
// once), 2-cycle break, race-free ping-pong pointer jumping, relabel, reset.
__global__ __launch_bounds__(256)
void k_merge(u64* __restrict__ compBest, int* __restrict__ comp,
             float* __restrict__ deathsD2, int* __restrict__ cnt) {
    __shared__ u64 scb[PH_N];      // 16 KB
    __shared__ int scm[PH_N];      // 8 KB
    __shared__ int sp[PH_N];       // 8 KB
    __shared__ int sq_[PH_N];      // 8 KB
    const int b = blockIdx.x, tid = threadIdx.x, T = 256;
    u64* cb = compBest + (size_t)b * PH_N;
    int* cm = comp + (size_t)b * PH_N;

    for (int i = tid; i < PH_N; i += T) { scb[i] = cb[i]; scm[i] = cm[i]; }
    __syncthreads();

    // phase 1: parent = target component (self if no outgoing edge)
    for (int c = tid; c < PH_N; c += T) {
        u64 k = scb[c];
        int pp = c;
        if (k != ~0ULL) {
            int a = (int)((k >> 11) & 0x7FF), d = (int)(k & 0x7FF);
            int ca = scm[a], cd = scm[d];
            pp = (ca == c) ? cd : ca;
        }
        sp[c] = pp;
    }
    __syncthreads();
    // phase 2a: record deaths (read-only on sp). Mutual pair = both picked the
    // SAME undirected edge (strict-total-order argument) -> smaller label records.
    for (int c = tid; c < PH_N; c += T) {
        u64 k = scb[c];
        if (k != ~0ULL) {
            int tc = sp[c];
            bool mutual = (sp[tc] == c);
            if (!mutual || c < tc) {
                int slot = atomicAdd(&cnt[b], 1);
                deathsD2[(size_t)b * PH_N + slot] = __uint_as_float((u32)(k >> 22));
            }
        }
    }
    __syncthreads();
    // phase 2b: break 2-cycles (smaller label becomes root). Race-benign: the
    // larger side's write condition is false under either read order.
    for (int c = tid; c < PH_N; c += T) {
        u64 k = scb[c];
        if (k != ~0ULL) {
            int tc = sp[c];
            if (sp[tc] == c && c < tc) sp[c] = c;
        }
    }
    __syncthreads();
    // phase 3: pointer jumping, ping-pong (race-free); p^(2^12) covers N=2048
    int* cur = sp; int* nxt = sq_;
    for (int it = 0; it < 12; ++it) {
        for (int c = tid; c < PH_N; c += T) nxt[c] = cur[cur[c]];
        __syncthreads();
        int* t = cur; cur = nxt; nxt = t;
    }
    // phase 4: relabel vertices to roots; phase 5: reset for next round
    for (int v = tid; v < PH_N; v += T) cm[v] = cur[scm[v]];
    for (int c = tid; c < PH_N; c += T) cb[c] = ~0ULL;
}

__global__ __launch_bounds__(256)
void k_final(const float* __restrict__ deathsD2, const float* __restrict__ filt,
             float* __restrict__ out) {
    __shared__ float deaths[PH_N];
    __shared__ int   scnt[PH_F];
    const int b = blockIdx.x, tid = threadIdx.x;
    const float INF = __builtin_inff();

    for (int t = tid; t < PH_N; t += 256) {
        deaths[t] = (t < PH_N - 1)
                        ? sqrtf(deathsD2[(size_t)b * PH_N + t])  // d2 pre-clamped >= 0
                        : -INF;                                  // pad
    }
    __syncthreads();

    // bitonic sort ascending
    for (int k = 2; k <= PH_N; k <<= 1) {
        for (int jj = k >> 1; jj > 0; jj >>= 1) {
            for (int i = tid; i < PH_N; i += 256) {
                int ixj = i ^ jj;
                if (ixj > i) {
                    float a = deaths[i];
                    float c = deaths[ixj];
                    bool up = ((i & k) == 0);
                    if (up ? (a > c) : (a < c)) {
                        deaths[i]   = c;
                        deaths[ixj] = a;
                    }
                }
            }
            __syncthreads();
        }
    }

    if (tid < PH_F) {
        float eps = filt[tid];
        int lo = 0, hi = PH_N;
        while (lo < hi) {
            int mid = (lo + hi) >> 1;
            if (deaths[mid] <= eps) lo = mid + 1; else hi = mid;
        }
        scnt[tid] = lo - 1;   // exclude -inf pad
    }
    __syncthreads();

    float* dg = out + (size_t)b * (3 * MAXPTS * 2);
    for (int t = tid; t < 3 * MAXPTS * 2; t += 256) {
        float val = 0.0f;
        if (t < 2 * MAXPTS && (t & 1)) {
            int k = t >> 1;
            val = deaths[PH_N - 1 - k];
        }
        dg[t] = val;
    }
    float* bc = out + (size_t)PH_B * (3 * MAXPTS * 2) + (size_t)b * (3 * PH_F);
    for (int t = tid; t < 3 * PH_F; t += 256) {
        float val = 0.0f;
        if (t < PH_F) val = (float)(PH_N - scnt[t]);
        bc[t] = val;
    }
}

extern "C" void kernel_launch(void* const* d_in, const int* in_sizes, int n_in,
                              void* d_out, int out_size, void* d_ws, size_t ws_size,
                              hipStream_t stream) {
    const float* x    = (const float*)d_in[0];
    const float* filt = (const float*)d_in[1];
    float* out        = (float*)d_out;

    char* ws = (char*)d_ws;                       // needs ~513 KB
    u64*   compBest = (u64*)ws;                   // [B][N] u64
    int*   comp     = (int*)(ws + (size_t)PH_B * PH_N * 8);
    float* dD2      = (float*)(comp + PH_B * PH_N);
    int*   cnt      = (int*)(dD2 + PH_B * PH_N);

    k_init<<<PH_B, 256, 0, stream>>>(comp, compBest, cnt);
    for (int r = 0; r < ROUNDS; ++r) {
        k_best<<<dim3(RB, PH_B), KA_TPB, 0, stream>>>(x, comp, compBest);
        k_merge<<<PH_B, 256, 0, stream>>>(compBest, comp, dD2, cnt);
    }
    k_final<<<PH_B, 256, 0, stream>>>(dD2, filt, out);
}

// Round 9
// 329.289 us; speedup vs baseline: 5.9579x; 1.3566x over previous
//
#include <hip/hip_runtime.h>
#include <math.h>

// Boruvka MST persistent-homology kernel.
// Correctness: all MSTs under a strict total edge order share the MST; the
// death outputs depend only on the MST weight multiset, which is identical
// for ALL MSTs under any tie-break refinement. We order edges by the key
// (d2_bits, min(i,j), max(i,j)) — a strict refinement of the reference's
// sqrt-domain weight order (sqrtf is correctly rounded => monotone). d2 is
// computed in the reference's exact f32 op order and clamped, sqrtf applied
// once at the end => bit-exact outputs vs the reference's Prim.
// Per-row tie-break: for fixed row i, minimizing the full key on equal d2
// equals picking the smallest j (case split on min/max(i,j)) — implemented
// as lowest-k in-lane + cross-lane DPP int-min over j among d2-tied lanes.

#define PH_N   2048
#define PH_B   16
#define PH_F   50
#define MAXPTS 100
#define ROUNDS 11            // ceil(log2(N)) guaranteed convergence
#define RB     16            // row-blocks per batch in k_best
#define RPB    (PH_N / RB)   // 128 rows per block
#define KA_TPB 256
#define JPL    32            // j's per lane (2048/64)

typedef unsigned long long u64;
typedef unsigned int u32;

__device__ __forceinline__ float sq3(float x, float y, float z) {
    return __fadd_rn(__fadd_rn(__fmul_rn(x, x), __fmul_rn(y, y)), __fmul_rn(z, z));
}
// d2 exactly as reference: (sq_p + sq_q) - 2*dot, no fma contraction
__device__ __forceinline__ float d2f(float px, float py, float pz, float ps,
                                     float qx, float qy, float qz, float qs) {
    float dot = __fadd_rn(__fadd_rn(__fmul_rn(px, qx), __fmul_rn(py, qy)),
                          __fmul_rn(pz, qz));
    return __fsub_rn(__fadd_rn(ps, qs), __fmul_rn(2.0f, dot));
}

template<int CTRL>
__device__ __forceinline__ float dpp_min(float v) {
    int vi = __float_as_int(v);
    int sh = __builtin_amdgcn_update_dpp(vi, vi, CTRL, 0xF, 0xF, false);
    return fminf(v, __int_as_float(sh));
}
template<int CTRL>
__device__ __forceinline__ int dpp_imin(int v) {
    int sh = __builtin_amdgcn_update_dpp(v, v, CTRL, 0xF, 0xF, false);
    return min(v, sh);
}

__global__ void k_init(int* __restrict__ comp, u64* __restrict__ compBest,
                       int* __restrict__ cnt) {
    const int b = blockIdx.x, tid = threadIdx.x;
    for (int i = tid; i < PH_N; i += blockDim.x) {
        comp[b * PH_N + i]     = i;
        compBest[b * PH_N + i] = ~0ULL;
    }
    if (tid == 0) cnt[b] = 0;
}

// Per round: each vertex (row i) finds its min-key edge to another component;
// per-component min via LDS u64 atomicMin, then merged to global.
__global__ __launch_bounds__(KA_TPB, 1)
void k_best(const float* __restrict__ x, const int* __restrict__ comp,
            u64* __restrict__ compBest) {
    __shared__ float4 spts[PH_N];    // 32 KB {x,y,z,|p|^2}
    __shared__ int    scomp[PH_N];   // 8 KB
    __shared__ u64    sbest[PH_N];   // 16 KB

    const int b = blockIdx.y, rb = blockIdx.x, tid = threadIdx.x;
    const int lane = tid & 63, wave = tid >> 6;
    const float* xb = x + (size_t)b * PH_N * 3;

    // stage labels first; converged rounds bail before the heavy staging
    for (int i = tid; i < PH_N; i += KA_TPB) scomp[i] = comp[b * PH_N + i];
    __syncthreads();
    {
        int c0 = scomp[0], diff = 0;
        for (int i = tid; i < PH_N; i += KA_TPB) diff |= (scomp[i] != c0);
        if (!__syncthreads_or(diff)) return;
    }

    for (int i = tid; i < PH_N; i += KA_TPB) {
        float px = xb[3 * i], py = xb[3 * i + 1], pz = xb[3 * i + 2];
        spts[i]  = make_float4(px, py, pz, sq3(px, py, pz));
        sbest[i] = ~0ULL;
    }
    __syncthreads();

    // per-lane j-side caches in registers (lane owns j = lane + 64k)
    float xj[JPL], yj[JPL], zj[JPL], sj[JPL];
    int   cj[JPL];
    #pragma unroll
    for (int k = 0; k < JPL; ++k) {
        float4 qv = spts[lane + (k << 6)];
        xj[k] = qv.x; yj[k] = qv.y; zj[k] = qv.z; sj[k] = qv.w;
        cj[k] = scomp[lane + (k << 6)];
    }

    const float INF = __builtin_inff();
    for (int r = wave; r < RPB; r += KA_TPB / 64) {
        const int    i  = rb * RPB + r;
        const int    ci = scomp[i];
        const float4 pi = spts[i];
        float m[JPL]; int ix[JPL];
        #pragma unroll
        for (int k = 0; k < JPL; ++k) {
            float d2 = d2f(pi.x, pi.y, pi.z, pi.w, xj[k], yj[k], zj[k], sj[k]);
            d2   = fmaxf(d2, 0.0f);                 // = reference max(d2,0)
            m[k] = (cj[k] == ci) ? INF : d2;        // mask same-component (covers j==i)
            ix[k] = k;
        }
        // in-register argmin tree; on ties keeps lower k (= lower j per lane)
        #pragma unroll
        for (int s = JPL / 2; s > 0; s >>= 1) {
            #pragma unroll
            for (int k = 0; k < s; ++k)
                if (m[k + s] < m[k]) { m[k] = m[k + s]; ix[k] = ix[k + s]; }
        }
        const float vl = m[0];
        float w = vl;
        w = dpp_min<0x111>(w); w = dpp_min<0x112>(w); w = dpp_min<0x114>(w);
        w = dpp_min<0x118>(w); w = dpp_min<0x142>(w); w = dpp_min<0x143>(w);
        const float wm =
            __int_as_float(__builtin_amdgcn_readlane(__float_as_int(w), 63));
        if (wm < INF) {
            // full-key-consistent tie-break: among d2-tied lanes take min j
            int jw = lane + (ix[0] << 6);
            int jc = (vl == wm) ? jw : 0x7FFFFFFF;
            jc = dpp_imin<0x111>(jc); jc = dpp_imin<0x112>(jc);
            jc = dpp_imin<0x114>(jc); jc = dpp_imin<0x118>(jc);
            jc = dpp_imin<0x142>(jc); jc = dpp_imin<0x143>(jc);
            const int j = __builtin_amdgcn_readlane(jc, 63);
            if (lane == 0) {
                int a = min(i, j), c2 = max(i, j);
                u64 key = ((u64)__float_as_uint(wm) << 22) | ((u64)a << 11) | (u64)c2;
                atomicMin(&sbest[ci], key);
            }
        }
    }
    __syncthreads();
    for (int c = tid; c < PH_N; c += KA_TPB) {
        u64 k = sbest[c];
        if (k != ~0ULL) atomicMin(&compBest[(size_t)b * PH_N + c], k);
    }
}

// Merge (all in LDS): parent links, mutual-pair dedup (each MST edge recorded
// once), 2-cycle break, early-exit ping-pong pointer jumping, relabel, reset.
__global__ __launch_bounds__(1024)
void k_merge(u64* __restrict__ compBest, int* __restrict__ comp,
             float* __restrict__ deathsD2, int* __restrict__ cnt) {
    __shared__ u64 scb[PH_N];      // 16 KB
    __shared__ int scm[PH_N];      // 8 KB
    __shared__ int sp[PH_N];       // 8 KB
    __shared__ int sq_[PH_N];      // 8 KB
    const int b = blockIdx.x, tid = threadIdx.x, T = 1024;
    u64* cb = compBest + (size_t)b * PH_N;
    int* cm = comp + (size_t)b * PH_N;

    int any = 0;
    for (int i = tid; i < PH_N; i += T) {
        u64 k = cb[i];
        scb[i] = k; scm[i] = cm[i];
        any |= (k != ~0ULL);
    }
    // converged round: no picked edges anywhere -> comp/compBest unchanged
    if (!__syncthreads_or(any)) return;

    // phase 1: parent = target component (self if no outgoing edge)
    for (int c = tid; c < PH_N; c += T) {
        u64 k = scb[c];
        int pp = c;
        if (k != ~0ULL) {
            int a = (int)((k >> 11) & 0x7FF), d = (int)(k & 0x7FF);
            int ca = scm[a], cd = scm[d];
            pp = (ca == c) ? cd : ca;
        }
        sp[c] = pp;
    }
    __syncthreads();
    // phase 2a: record deaths (read-only on sp). Mutual pair = both picked the
    // SAME undirected edge (strict-total-order argument) -> smaller label records.
    for (int c = tid; c < PH_N; c += T) {
        u64 k = scb[c];
        if (k != ~0ULL) {
            int tc = sp[c];
            bool mutual = (sp[tc] == c);
            if (!mutual || c < tc) {
                int slot = atomicAdd(&cnt[b], 1);
                deathsD2[(size_t)b * PH_N + slot] = __uint_as_float((u32)(k >> 22));
            }
        }
    }
    __syncthreads();
    // phase 2b: break 2-cycles (smaller label becomes root). Race-benign: the
    // larger side's write condition is false under either read order.
    for (int c = tid; c < PH_N; c += T) {
        u64 k = scb[c];
        if (k != ~0ULL) {
            int tc = sp[c];
            if (sp[tc] == c && c < tc) sp[c] = c;
        }
    }
    __syncthreads();
    // phase 3: pointer jumping, ping-pong (race-free), early exit when stable.
    // __syncthreads_or doubles as the inter-pass barrier; uniform break.
    int* cur = sp; int* nxt = sq_;
    for (int it = 0; it < 12; ++it) {
        int changed = 0;
        for (int c = tid; c < PH_N; c += T) {
            int v = cur[cur[c]];
            nxt[c] = v;
            changed |= (v != cur[c]);
        }
        int* t = cur; cur = nxt; nxt = t;
        if (!__syncthreads_or(changed)) break;
    }
    // phase 4: relabel vertices to roots; phase 5: reset for next round
    for (int v = tid; v < PH_N; v += T) cm[v] = cur[scm[v]];
    for (int c = tid; c < PH_N; c += T) cb[c] = ~0ULL;
}

__global__ __launch_bounds__(1024)
void k_final(const float* __restrict__ deathsD2, const float* __restrict__ filt,
             float* __restrict__ out) {
    __shared__ float deaths[PH_N];
    __shared__ int   scnt[PH_F];
    const int b = blockIdx.x, tid = threadIdx.x, T = 1024;
    const float INF = __builtin_inff();

    for (int t = tid; t < PH_N; t += T) {
        deaths[t] = (t < PH_N - 1)
                        ? sqrtf(deathsD2[(size_t)b * PH_N + t])  // d2 pre-clamped >= 0
                        : -INF;                                  // pad
    }
    __syncthreads();

    // bitonic sort ascending (1024 threads -> ~1 compare-exchange per pass)
    for (int k = 2; k <= PH_N; k <<= 1) {
        for (int jj = k >> 1; jj > 0; jj >>= 1) {
            for (int i = tid; i < PH_N; i += T) {
                int ixj = i ^ jj;
                if (ixj > i) {
                    float a = deaths[i];
                    float c = deaths[ixj];
                    bool up = ((i & k) == 0);
                    if (up ? (a > c) : (a < c)) {
                        deaths[i]   = c;
                        deaths[ixj] = a;
                    }
                }
            }
            __syncthreads();
        }
    }

    if (tid < PH_F) {
        float eps = filt[tid];
        int lo = 0, hi = PH_N;
        while (lo < hi) {
            int mid = (lo + hi) >> 1;
            if (deaths[mid] <= eps) lo = mid + 1; else hi = mid;
        }
        scnt[tid] = lo - 1;   // exclude -inf pad
    }
    __syncthreads();

    float* dg = out + (size_t)b * (3 * MAXPTS * 2);
    for (int t = tid; t < 3 * MAXPTS * 2; t += T) {
        float val = 0.0f;
        if (t < 2 * MAXPTS && (t & 1)) {
            int k = t >> 1;
            val = deaths[PH_N - 1 - k];
        }
        dg[t] = val;
    }
    float* bc = out + (size_t)PH_B * (3 * MAXPTS * 2) + (size_t)b * (3 * PH_F);
    for (int t = tid; t < 3 * PH_F; t += T) {
        float val = 0.0f;
        if (t < PH_F) val = (float)(PH_N - scnt[t]);
        bc[t] = val;
    }
}

extern "C" void kernel_launch(void* const* d_in, const int* in_sizes, int n_in,
                              void* d_out, int out_size, void* d_ws, size_t ws_size,
                              hipStream_t stream) {
    const float* x    = (const float*)d_in[0];
    const float* filt = (const float*)d_in[1];
    float* out        = (float*)d_out;

    char* ws = (char*)d_ws;                       // needs ~513 KB
    u64*   compBest = (u64*)ws;                   // [B][N] u64
    int*   comp     = (int*)(ws + (size_t)PH_B * PH_N * 8);
    float* dD2      = (float*)(comp + PH_B * PH_N);
    int*   cnt      = (int*)(dD2 + PH_B * PH_N);

    k_init<<<PH_B, 256, 0, stream>>>(comp, compBest, cnt);
    for (int r = 0; r < ROUNDS; ++r) {
        k_best<<<dim3(RB, PH_B), KA_TPB, 0, stream>>>(x, comp, compBest);
        k_merge<<<PH_B, 1024, 0, stream>>>(compBest, comp, dD2, cnt);
    }
    k_final<<<PH_B, 1024, 0, stream>>>(dD2, filt, out);
}